// Round 7
// baseline (452.317 us; speedup 1.0000x reference)
//
#include <hip/hip_runtime.h>

typedef __attribute__((ext_vector_type(4))) float  f32x4;
typedef __attribute__((ext_vector_type(4))) short  s16x4;
typedef __attribute__((ext_vector_type(4))) int    i32x4;

#define MFMAI8(a, b, c) __builtin_amdgcn_mfma_i32_16x16x64_i8((a), (b), (c), 0, 0, 0)

__device__ __forceinline__ void gload_lds16(const void* g, void* l) {
  __builtin_amdgcn_global_load_lds((const __attribute__((address_space(1))) void*)g,
                                   (__attribute__((address_space(3))) void*)l, 16, 0, 0);
}

__device__ __forceinline__ char sgn8(float v) {
  return v > 0.f ? (char)1 : (v < 0.f ? (char)-1 : (char)0);
}

// ---------------------------------------------------------------------------
// prep_w: per-oc scale = mean|w|; sign(w) as int8.
// ---------------------------------------------------------------------------
__global__ __launch_bounds__(256) void prep_w(const float* __restrict__ w3,
                                              const float* __restrict__ wpw,
                                              char* __restrict__ w1s,
                                              char* __restrict__ w2s,
                                              float* __restrict__ scale1,
                                              float* __restrict__ scale2) {
  const int o = blockIdx.x;
  const int t = threadIdx.x;
  float s = 0.f;
  if (blockIdx.y == 0) {
    for (int u = t; u < 2304; u += 256) {
      int i = u / 9, tap = u % 9;
      float v = w3[(size_t)(o * 256 + i) * 9 + tap];
      s += fabsf(v);
      w1s[(size_t)(tap * 256 + o) * 256 + i] = sgn8(v);
    }
  } else {
    float v = wpw[o * 256 + t];
    s = fabsf(v);
    w2s[o * 256 + t] = sgn8(v);
  }
  for (int m = 1; m < 64; m <<= 1) s += __shfl_xor(s, m);
  __shared__ float red[4];
  if ((t & 63) == 0) red[t >> 6] = s;
  __syncthreads();
  if (t == 0) {
    float tot = red[0] + red[1] + red[2] + red[3];
    if (blockIdx.y == 0) scale1[o] = tot / 2304.f;
    else                 scale2[o] = tot / 256.f;
  }
}

// ---------------------------------------------------------------------------
// sign_nhwc: s1[n][h][w][c] = i8 sign(x[n][c][h][w] + b11[c])
// ---------------------------------------------------------------------------
__global__ __launch_bounds__(256) void sign_nhwc(const float* __restrict__ x,
                                                 const float* __restrict__ b11,
                                                 char* __restrict__ out) {
  __shared__ unsigned short l[56 * 128];  // [w][cpair]
  __shared__ float cB[256];
  const int h = blockIdx.x, n = blockIdx.y, t = threadIdx.x;
  cB[t] = b11[t];
  __syncthreads();
  const int wv = t & 15, cg = t >> 4;
  if (wv < 14) {
    const int w0 = wv * 4;
    const int swz = (wv & 7) << 3;
#pragma unroll 4
    for (int it = 0; it < 8; ++it) {
      int cp = it * 16 + cg;
      int c0 = cp * 2;
      size_t i0 = (size_t)(n * 256 + c0) * 3136 + h * 56 + w0;
      f32x4 x0 = *(const f32x4*)(x + i0);
      f32x4 x1 = *(const f32x4*)(x + i0 + 3136);
      float bb0 = cB[c0], bb1 = cB[c0 + 1];
      int cs = cp ^ swz;
#pragma unroll
      for (int j = 0; j < 4; ++j) {
        unsigned short pk = (unsigned char)sgn8(x0[j] + bb0) |
                            ((unsigned short)(unsigned char)sgn8(x1[j] + bb1) << 8);
        l[(w0 + j) * 128 + cs] = pk;
      }
    }
  }
  __syncthreads();
  char* op = out + ((size_t)(n * 56 + h) * 56) * 256;
  for (int u = t; u < 56 * 16; u += 256) {
    int w2 = u >> 4, cp = u & 15;
    *(i32x4*)(op + w2 * 256 + cp * 16) =
        *(const i32x4*)&l[w2 * 128 + ((cp * 8) ^ (((w2 >> 2) & 7) << 3))];
  }
}

// ---------------------------------------------------------------------------
// conv3x3 (i8): implicit-GEMM 3x3 pad1, T14 reg-staged single-buffer pipeline.
// LDS = lin 37120 + lw 36864 = 73984 B -> 2 blocks/CU. NO global_load_lds:
// phase p issues ~19 plain global loads -> regs (full compute phase to land),
// compute reads LDS, barrier, ds_write regs->LDS, barrier. No vmcnt coupling.
// Epilogue: LDS-transpose then dwordx4 stores (64B runs per oc).
// ---------------------------------------------------------------------------
__global__ __launch_bounds__(256, 2) void conv3x3(const char* __restrict__ sIn,
                                                  const char* __restrict__ wSgn,
                                                  short* __restrict__ raw,
                                                  float* __restrict__ S,
                                                  float* __restrict__ SS) {
  __shared__ char lin[10 * 58 * 64];   // [row10][col58][64 ic-bytes] 37120 B
  __shared__ char lw[9 * 64 * 64];     // [tap9][oc64][64 ic-bytes]   36864 B

  int bid = (blockIdx.x & 7) * 112 + (blockIdx.x >> 3);  // XCD-chunked, bijective
  const int ot = bid & 3;
  const int g  = bid >> 2;
  const int ht = g % 7, n = g / 7;
  const int h0 = ht * 8, oc0 = ot * 64;

  const int t = threadIdx.x;
  const int lane = t & 63, wv = t >> 6;
  const int cl = lane & 15, kk = lane >> 4;

  const int pw = t >> 2, sl = t & 3;
  const int srcslot = sl ^ (((1 + pw) >> 1) & 3);

  // zero halo cols 0 and 57 once (never touched by stages)
  if (t < 80) {
    int rr = t >> 3, q = t & 7;
    int col = (q >> 2) ? 57 : 0;
    *(i32x4*)&lin[(rr * 58 + col) * 64 + (q & 3) * 16] = (i32x4){0, 0, 0, 0};
  }

  i32x4 inreg[10], wreg[9];

#define LOADR(icc)                                                               \
  {                                                                              \
    if (t < 224) {                                                               \
      _Pragma("unroll")                                                          \
      for (int rr = 0; rr < 10; ++rr) {                                          \
        int h = h0 - 1 + rr;                                                     \
        if (h >= 0 && h < 56)                                                    \
          inreg[rr] = *(const i32x4*)(sIn +                                      \
              ((size_t)((n * 56 + h) * 56 + pw) * 256 + (icc) * 64 + srcslot * 16)); \
        else                                                                     \
          inreg[rr] = (i32x4){0, 0, 0, 0};                                       \
      }                                                                          \
    }                                                                            \
    _Pragma("unroll")                                                            \
    for (int i = 0; i < 9; ++i) {                                                \
      int u = i * 256 + t;                                                       \
      int tap = u >> 8, oc_e = (u >> 2) & 63;                                    \
      int wslot = (u & 3) ^ ((u >> 3) & 3);                                      \
      wreg[i] = *(const i32x4*)(wSgn +                                           \
          ((size_t)(tap * 256 + oc0 + oc_e) * 256 + (icc) * 64 + wslot * 16));   \
    }                                                                            \
  }

#define WRITER()                                                                 \
  {                                                                              \
    if (t < 224) {                                                               \
      _Pragma("unroll")                                                          \
      for (int rr = 0; rr < 10; ++rr)                                            \
        *(i32x4*)&lin[(rr * 58 + 1 + pw) * 64 + sl * 16] = inreg[rr];            \
    }                                                                            \
    _Pragma("unroll")                                                            \
    for (int i = 0; i < 9; ++i)                                                  \
      *(i32x4*)&lw[(i * 256 + t) * 16] = wreg[i];                                \
  }

  int r0[7], c0[7];
#pragma unroll
  for (int nf = 0; nf < 7; ++nf) {
    int p = wv * 112 + nf * 16 + cl;
    r0[nf] = p / 56;
    c0[nf] = p % 56;
  }

  i32x4 acc[4][7];
#pragma unroll
  for (int m = 0; m < 4; ++m)
#pragma unroll
    for (int nf = 0; nf < 7; ++nf) acc[m][nf] = (i32x4){0, 0, 0, 0};

  LOADR(0);
  WRITER();          // disjoint from halo-zero writes; no barrier needed between
  __syncthreads();   // phase-0 data visible

  for (int icc = 0; icc < 4; ++icc) {
    if (icc < 3) LOADR(icc + 1);  // plain global loads; land during compute

#pragma unroll
    for (int kh = 0; kh < 3; ++kh)
#pragma unroll
      for (int kw = 0; kw < 3; ++kw) {
        const int tap = kh * 3 + kw;
        i32x4 a[4];
#pragma unroll
        for (int m = 0; m < 4; ++m)
          a[m] = *(const i32x4*)(&lw[(tap * 64 + m * 16 + cl) * 64 +
                                     ((kk ^ ((cl >> 1) & 3)) << 4)]);
#pragma unroll
        for (int nf = 0; nf < 7; ++nf) {
          int col = c0[nf] + kw;
          int addr = ((r0[nf] + kh) * 58 + col) * 64 + ((kk ^ ((col >> 1) & 3)) << 4);
          i32x4 b = *(const i32x4*)(&lin[addr]);
#pragma unroll
          for (int m = 0; m < 4; ++m) acc[m][nf] = MFMAI8(a[m], b, acc[m][nf]);
        }
      }
    __syncthreads();            // all reads of lin/lw done
    if (icc < 3) {
      WRITER();
      __syncthreads();          // next-phase data visible
    }
  }

  // ---- epilogue: stats + LDS-transpose + coalesced dwordx4 stores ----
  unsigned short* tb = (unsigned short*)lin;  // 16 x 472 u16 = 15104 B, 16B-aligned rows
  const size_t ocbase = (size_t)n * 256 + oc0;
#pragma unroll
  for (int m = 0; m < 4; ++m) {
    float sm[4] = {0.f, 0.f, 0.f, 0.f}, sq[4] = {0.f, 0.f, 0.f, 0.f};
#pragma unroll
    for (int nf = 0; nf < 7; ++nf) {
      i32x4 v = acc[m][nf];
#pragma unroll
      for (int r2 = 0; r2 < 4; ++r2) {
        float fv = (float)v[r2];
        sm[r2] += fv;
        sq[r2] += fv * fv;
      }
    }
#pragma unroll
    for (int r2 = 0; r2 < 4; ++r2) {
      float aa = sm[r2], qq = sq[r2];
      aa += __shfl_xor(aa, 1); qq += __shfl_xor(qq, 1);
      aa += __shfl_xor(aa, 2); qq += __shfl_xor(qq, 2);
      aa += __shfl_xor(aa, 4); qq += __shfl_xor(qq, 4);
      aa += __shfl_xor(aa, 8); qq += __shfl_xor(qq, 8);
      if (cl == 0) {
        int oc = oc0 + m * 16 + kk * 4 + r2;
        atomicAdd(&S[oc], aa);
        atomicAdd(&SS[oc], qq);
      }
    }
    __syncthreads();  // prev-m tb reads (or final compute) done
#pragma unroll
    for (int nf = 0; nf < 7; ++nf) {
      i32x4 v = acc[m][nf];
      int px = wv * 112 + nf * 16 + cl;
#pragma unroll
      for (int r2 = 0; r2 < 4; ++r2)
        tb[(kk * 4 + r2) * 472 + px] = (unsigned short)(short)v[r2];
    }
    __syncthreads();
    for (int u = t; u < 896; u += 256) {
      int qc = u >> 6, r = u & 63, ocl = r >> 2, c3 = r & 3;
      int c8 = qc * 4 + c3;
      *(i32x4*)(raw + (ocbase + m * 16 + ocl) * 3136 + h0 * 56 + c8 * 8) =
          *(const i32x4*)&tb[ocl * 472 + c8 * 8];
    }
  }
}

// ---------------------------------------------------------------------------
// conv1x1 (i8): stage FULL 112px x 256ic input once (gload_lds, px-keyed XOR),
// ONE staging barrier; weights direct global->VGPR (issued after the drain, so
// no vmcnt coupling). Epilogue: LDS-transpose + coalesced stores.
// ---------------------------------------------------------------------------
__global__ __launch_bounds__(256, 2) void conv1x1(const char* __restrict__ sIn,
                                                  const char* __restrict__ wSgn,
                                                  short* __restrict__ raw,
                                                  float* __restrict__ S,
                                                  float* __restrict__ SS) {
  __shared__ char lin[112 * 256];  // 28672 B

  const int b = blockIdx.x;            // 896 = 32 n * 28 px-groups
  const int n = b / 28;
  const int hw0 = (b % 28) * 112;
  const size_t px0 = (size_t)n * 3136 + hw0;
  const int t = threadIdx.x, lane = t & 63, wv = t >> 6;
  const int cl = lane & 15, kk = lane >> 4;

#pragma unroll
  for (int i = 0; i < 7; ++i) {
    int u = i * 256 + t;
    int px = u >> 4, s = u & 15;
    const char* src = sIn + (px0 + px) * 256 + ((s ^ (px & 7)) * 16);
    gload_lds16(src, lin + u * 16);
  }

  i32x4 acc[4][7];
#pragma unroll
  for (int m = 0; m < 4; ++m)
#pragma unroll
    for (int nf = 0; nf < 7; ++nf) acc[m][nf] = (i32x4){0, 0, 0, 0};

  __syncthreads();  // staging drained; LDS read-only below

#pragma unroll
  for (int icc = 0; icc < 4; ++icc) {
    i32x4 bfr[7];
#pragma unroll
    for (int nf = 0; nf < 7; ++nf) {
      int px = nf * 16 + cl;
      int srd = (icc * 4 + kk) ^ (px & 7);
      bfr[nf] = *(const i32x4*)(lin + px * 256 + srd * 16);
    }
#pragma unroll
    for (int m = 0; m < 4; ++m) {
      i32x4 a = *(const i32x4*)(wSgn +
          (((size_t)(wv * 64 + m * 16 + cl)) << 8) + icc * 64 + kk * 16);
#pragma unroll
      for (int nf = 0; nf < 7; ++nf) acc[m][nf] = MFMAI8(a, bfr[nf], acc[m][nf]);
    }
  }

  __syncthreads();  // all lin reads done; reuse as transpose buffer
  unsigned short* tb = (unsigned short*)lin;  // 64 rows x 120 u16 = 15360 B
#pragma unroll
  for (int m = 0; m < 4; ++m) {
    float sm[4] = {0.f, 0.f, 0.f, 0.f}, sq[4] = {0.f, 0.f, 0.f, 0.f};
#pragma unroll
    for (int nf = 0; nf < 7; ++nf) {
      i32x4 v = acc[m][nf];
#pragma unroll
      for (int r2 = 0; r2 < 4; ++r2) {
        float fv = (float)v[r2];
        sm[r2] += fv;
        sq[r2] += fv * fv;
      }
    }
#pragma unroll
    for (int r2 = 0; r2 < 4; ++r2) {
      float aa = sm[r2], qq = sq[r2];
      aa += __shfl_xor(aa, 1); qq += __shfl_xor(qq, 1);
      aa += __shfl_xor(aa, 2); qq += __shfl_xor(qq, 2);
      aa += __shfl_xor(aa, 4); qq += __shfl_xor(qq, 4);
      aa += __shfl_xor(aa, 8); qq += __shfl_xor(qq, 8);
      if (cl == 0) {
        int oc = wv * 64 + m * 16 + kk * 4 + r2;
        atomicAdd(&S[oc], aa);
        atomicAdd(&SS[oc], qq);
      }
    }
    __syncthreads();
#pragma unroll
    for (int nf = 0; nf < 7; ++nf) {
      i32x4 v = acc[m][nf];
      int px = nf * 16 + cl;
#pragma unroll
      for (int r2 = 0; r2 < 4; ++r2)
        tb[(wv * 16 + kk * 4 + r2) * 120 + px] = (unsigned short)(short)v[r2];
    }
    __syncthreads();
#pragma unroll
    for (int i = 0; i < 4; ++i) {
      int u = i * 256 + t;
      int ocg = u >> 4, c8 = u & 15;
      if (c8 < 14) {
        int oc = (ocg >> 4) * 64 + m * 16 + (ocg & 15);
        *(i32x4*)(raw + ((size_t)n * 256 + oc) * 3136 + hw0 + c8 * 8) =
            *(const i32x4*)&tb[ocg * 120 + c8 * 8];
      }
    }
  }
}

// ---------------------------------------------------------------------------
// bn_coef: fold stats + scale + BN affine + following bias into A*raw + B
// ---------------------------------------------------------------------------
__global__ void bn_coef(const float* __restrict__ S, const float* __restrict__ SS,
                        const float* __restrict__ scale, const float* __restrict__ g,
                        const float* __restrict__ be, const float* __restrict__ bext,
                        float* __restrict__ A, float* __restrict__ B) {
  int o = threadIdx.x;
  const float invN = 1.f / 100352.f;
  float mu_r  = S[o] * invN;
  float var_r = SS[o] * invN - mu_r * mu_r;
  float sc    = scale[o];
  float rstd  = rsqrtf(sc * sc * var_r + 1e-5f);
  A[o] = g[o] * rstd * sc;
  B[o] = be[o] - g[o] * rstd * sc * mu_r + bext[o];
}

// ---------------------------------------------------------------------------
// mid_fuse: u = prelu(x + A1*raw + B1', p1) + b13 -> t1 (d_out, NCHW f32)
//           s2 = i8 sign(u + b21) (NHWC, pair-packed LDS transpose)
// ---------------------------------------------------------------------------
__global__ __launch_bounds__(256) void mid_fuse(const short* __restrict__ raw,
                                                const float* __restrict__ x,
                                                const float* __restrict__ A1,
                                                const float* __restrict__ B1,
                                                const float* __restrict__ p1,
                                                const float* __restrict__ b13,
                                                const float* __restrict__ b21,
                                                float* __restrict__ t1,
                                                char* __restrict__ s2) {
  __shared__ unsigned short l[56 * 128];
  __shared__ float cA[256], cB[256], cP[256], cD[256], cE[256];
  const int h = blockIdx.x, n = blockIdx.y, t = threadIdx.x;
  cA[t] = A1[t]; cB[t] = B1[t]; cP[t] = p1[t]; cD[t] = b13[t]; cE[t] = b21[t];
  __syncthreads();
  const int wv = t & 15, cg = t >> 4;
  if (wv < 14) {
    const int w0 = wv * 4;
    const int swz = (wv & 7) << 3;
#pragma unroll 2
    for (int it = 0; it < 8; ++it) {
      int cp = it * 16 + cg;
      int c0 = cp * 2;
      size_t i0 = (size_t)(n * 256 + c0) * 3136 + h * 56 + w0;
      f32x4 x0 = *(const f32x4*)(x + i0);
      f32x4 x1 = *(const f32x4*)(x + i0 + 3136);
      s16x4 r0 = *(const s16x4*)(raw + i0);
      s16x4 r1 = *(const s16x4*)(raw + i0 + 3136);
      float a0 = cA[c0], b0 = cB[c0], p0 = cP[c0], d0 = cD[c0], e0 = cE[c0];
      float a1 = cA[c0+1], b1 = cB[c0+1], p1v = cP[c0+1], d1 = cD[c0+1], e1 = cE[c0+1];
      f32x4 o0, o1;
      int cs = cp ^ swz;
#pragma unroll
      for (int j = 0; j < 4; ++j) {
        float u0 = x0[j] + a0 * (float)r0[j] + b0;
        u0 = (u0 >= 0.f ? u0 : p0 * u0) + d0;
        o0[j] = u0;
        float u1 = x1[j] + a1 * (float)r1[j] + b1;
        u1 = (u1 >= 0.f ? u1 : p1v * u1) + d1;
        o1[j] = u1;
        unsigned short pk = (unsigned char)sgn8(u0 + e0) |
                            ((unsigned short)(unsigned char)sgn8(u1 + e1) << 8);
        l[(w0 + j) * 128 + cs] = pk;
      }
      *(f32x4*)(t1 + i0) = o0;
      *(f32x4*)(t1 + i0 + 3136) = o1;
    }
  }
  __syncthreads();
  char* op = s2 + ((size_t)(n * 56 + h) * 56) * 256;
  for (int u = t; u < 56 * 16; u += 256) {
    int w2 = u >> 4, cp = u & 15;
    *(i32x4*)(op + w2 * 256 + cp * 16) =
        *(const i32x4*)&l[w2 * 128 + ((cp * 8) ^ (((w2 >> 2) & 7) << 3))];
  }
}

// ---------------------------------------------------------------------------
// final_fuse: out = prelu(A2*raw + B2' + t1, p2) + b23  (block per (n,c) plane)
// ---------------------------------------------------------------------------
__global__ __launch_bounds__(256) void final_fuse(const short* __restrict__ raw,
                                                  const float* __restrict__ A2,
                                                  const float* __restrict__ B2,
                                                  const float* __restrict__ p2,
                                                  const float* __restrict__ b23,
                                                  float* out) {
  const int c = blockIdx.x & 255;
  const size_t base = (size_t)blockIdx.x * 3136;
  const float a = A2[c], b = B2[c], p = p2[c], d = b23[c];
  for (int i = threadIdx.x; i < 784; i += 256) {
    s16x4 r  = *(const s16x4*)(raw + base + (size_t)i * 4);
    f32x4 tt = *(const f32x4*)(out + base + (size_t)i * 4);
    f32x4 o;
#pragma unroll
    for (int j = 0; j < 4; ++j) {
      float v = a * (float)r[j] + b + tt[j];
      o[j] = (v >= 0.f ? v : p * v) + d;
    }
    *(f32x4*)(out + base + (size_t)i * 4) = o;
  }
}

// ---------------------------------------------------------------------------
extern "C" void kernel_launch(void* const* d_in, const int* in_sizes, int n_in,
                              void* d_out, int out_size, void* d_ws, size_t ws_size,
                              hipStream_t stream) {
  const float* x   = (const float*)d_in[0];
  const float* b11 = (const float*)d_in[1];
  const float* b12 = (const float*)d_in[2];
  const float* b13 = (const float*)d_in[3];
  const float* b21 = (const float*)d_in[4];
  const float* b22 = (const float*)d_in[5];
  const float* b23 = (const float*)d_in[6];
  const float* w3  = (const float*)d_in[7];
  const float* wpw = (const float*)d_in[8];
  const float* g1  = (const float*)d_in[9];
  const float* be1 = (const float*)d_in[10];
  const float* g2  = (const float*)d_in[11];
  const float* be2 = (const float*)d_in[12];
  const float* p1  = (const float*)d_in[13];
  const float* p2  = (const float*)d_in[14];

  char* ws = (char*)d_ws;
  short* raw    = (short*)(ws);                //  51,380,224 B
  char*  sgn    = (char*)(ws + 51380224);      //  25,690,112 B
  char*  w1s    = (char*)(ws + 77070336);      //     589,824 B
  char*  w2s    = (char*)(ws + 77660160);      //      65,536 B
  float* scale1 = (float*)(ws + 77725696);
  float* scale2 = (float*)(ws + 77726720);
  float* S1     = (float*)(ws + 77727744);
  float* SS1    = (float*)(ws + 77728768);
  float* S2     = (float*)(ws + 77729792);
  float* SS2    = (float*)(ws + 77730816);
  float* A1     = (float*)(ws + 77731840);
  float* B1     = (float*)(ws + 77732864);
  float* A2     = (float*)(ws + 77733888);
  float* B2     = (float*)(ws + 77734912);
  float* t1     = (float*)d_out;

  hipMemsetAsync(ws + 77727744, 0, 4096, stream);  // zero S1,SS1,S2,SS2

  prep_w<<<dim3(256, 2), 256, 0, stream>>>(w3, wpw, w1s, w2s, scale1, scale2);
  sign_nhwc<<<dim3(56, 32), 256, 0, stream>>>(x, b11, sgn);
  conv3x3<<<dim3(896), 256, 0, stream>>>(sgn, w1s, raw, S1, SS1);
  bn_coef<<<1, 256, 0, stream>>>(S1, SS1, scale1, g1, be1, b12, A1, B1);
  mid_fuse<<<dim3(56, 32), 256, 0, stream>>>(raw, x, A1, B1, p1, b13, b21, t1, sgn);
  conv1x1<<<dim3(896), 256, 0, stream>>>(sgn, w2s, raw, S2, SS2);
  bn_coef<<<1, 256, 0, stream>>>(S2, SS2, scale2, g2, be2, b22, A2, B2);
  final_fuse<<<dim3(8192), 256, 0, stream>>>(raw, A2, B2, p2, b23, (float*)d_out);
}

// Round 8
// 435.187 us; speedup vs baseline: 1.0394x; 1.0394x over previous
//
#include <hip/hip_runtime.h>

typedef __attribute__((ext_vector_type(4))) float  f32x4;
typedef __attribute__((ext_vector_type(4))) short  s16x4;
typedef __attribute__((ext_vector_type(4))) int    i32x4;

#define MFMAI8(a, b, c) __builtin_amdgcn_mfma_i32_16x16x64_i8((a), (b), (c), 0, 0, 0)

__device__ __forceinline__ void gload_lds16(const void* g, void* l) {
  __builtin_amdgcn_global_load_lds((const __attribute__((address_space(1))) void*)g,
                                   (__attribute__((address_space(3))) void*)l, 16, 0, 0);
}

__device__ __forceinline__ char sgn8(float v) {
  return v > 0.f ? (char)1 : (v < 0.f ? (char)-1 : (char)0);
}

// ---------------------------------------------------------------------------
// prep_w: per-oc scale = mean|w|; sign(w) as int8.
// ---------------------------------------------------------------------------
__global__ __launch_bounds__(256) void prep_w(const float* __restrict__ w3,
                                              const float* __restrict__ wpw,
                                              char* __restrict__ w1s,
                                              char* __restrict__ w2s,
                                              float* __restrict__ scale1,
                                              float* __restrict__ scale2) {
  const int o = blockIdx.x;
  const int t = threadIdx.x;
  float s = 0.f;
  if (blockIdx.y == 0) {
    for (int u = t; u < 2304; u += 256) {
      int i = u / 9, tap = u % 9;
      float v = w3[(size_t)(o * 256 + i) * 9 + tap];
      s += fabsf(v);
      w1s[(size_t)(tap * 256 + o) * 256 + i] = sgn8(v);
    }
  } else {
    float v = wpw[o * 256 + t];
    s = fabsf(v);
    w2s[o * 256 + t] = sgn8(v);
  }
  for (int m = 1; m < 64; m <<= 1) s += __shfl_xor(s, m);
  __shared__ float red[4];
  if ((t & 63) == 0) red[t >> 6] = s;
  __syncthreads();
  if (t == 0) {
    float tot = red[0] + red[1] + red[2] + red[3];
    if (blockIdx.y == 0) scale1[o] = tot / 2304.f;
    else                 scale2[o] = tot / 256.f;
  }
}

// ---------------------------------------------------------------------------
// sign_nhwc: s1[n][h][w][c] = i8 sign(x[n][c][h][w] + b11[c])
// ---------------------------------------------------------------------------
__global__ __launch_bounds__(256) void sign_nhwc(const float* __restrict__ x,
                                                 const float* __restrict__ b11,
                                                 char* __restrict__ out) {
  __shared__ unsigned short l[56 * 128];  // [w][cpair]
  __shared__ float cB[256];
  const int h = blockIdx.x, n = blockIdx.y, t = threadIdx.x;
  cB[t] = b11[t];
  __syncthreads();
  const int wv = t & 15, cg = t >> 4;
  if (wv < 14) {
    const int w0 = wv * 4;
    const int swz = (wv & 7) << 3;
#pragma unroll 4
    for (int it = 0; it < 8; ++it) {
      int cp = it * 16 + cg;
      int c0 = cp * 2;
      size_t i0 = (size_t)(n * 256 + c0) * 3136 + h * 56 + w0;
      f32x4 x0 = *(const f32x4*)(x + i0);
      f32x4 x1 = *(const f32x4*)(x + i0 + 3136);
      float bb0 = cB[c0], bb1 = cB[c0 + 1];
      int cs = cp ^ swz;
#pragma unroll
      for (int j = 0; j < 4; ++j) {
        unsigned short pk = (unsigned char)sgn8(x0[j] + bb0) |
                            ((unsigned short)(unsigned char)sgn8(x1[j] + bb1) << 8);
        l[(w0 + j) * 128 + cs] = pk;
      }
    }
  }
  __syncthreads();
  char* op = out + ((size_t)(n * 56 + h) * 56) * 256;
  for (int u = t; u < 56 * 16; u += 256) {
    int w2 = u >> 4, cp = u & 15;
    *(i32x4*)(op + w2 * 256 + cp * 16) =
        *(const i32x4*)&l[w2 * 128 + ((cp * 8) ^ (((w2 >> 2) & 7) << 3))];
  }
}

// ---------------------------------------------------------------------------
// conv3x3 (i8): input dbuf via gload_lds (74,240 B -> 2 blocks/CU); weights
// DIRECT global->VGPR per tap, depth-2 rotation (wA/wB, 32 regs). Taps 0-1
// issued BEFORE the staging stream so their vmcnt waits don't drain it; taps
// 2+ issued >=2 taps ahead. Exact int64 BN stats. Vec-store epilogue.
// ---------------------------------------------------------------------------
__global__ __launch_bounds__(256, 2) void conv3x3(const char* __restrict__ sIn,
                                                  const char* __restrict__ wSgn,
                                                  short* __restrict__ raw,
                                                  long long* __restrict__ S,
                                                  long long* __restrict__ SS) {
  __shared__ char lin[2][10 * 58 * 64];  // 37120 B per buf

  int bid = (blockIdx.x & 7) * 112 + (blockIdx.x >> 3);  // XCD-chunked, bijective
  const int ot = bid & 3;
  const int g  = bid >> 2;
  const int ht = g % 7, n = g / 7;
  const int h0 = ht * 8, oc0 = ot * 64;

  const int t = threadIdx.x;
  const int lane = t & 63, wv = t >> 6;
  const int cl = lane & 15, kk = lane >> 4;

  // zero halo cols 0 and 57 of BOTH buffers once (never touched by stages)
  if (t < 160) {
    int bi = t / 80, r = t % 80;
    int rr = r >> 3, q = r & 7;
    int col = (q >> 2) ? 57 : 0;
    *(i32x4*)&lin[bi][(rr * 58 + col) * 64 + (q & 3) * 16] = (i32x4){0, 0, 0, 0};
  }
  __syncthreads();

  const int pw = t >> 2, sl = t & 3;
  const int srcslot = sl ^ (((1 + pw) >> 1) & 3);

#define STAGE_3x3(icc, bi)                                                          \
  {                                                                                 \
    if (t < 224) {                                                                  \
      _Pragma("unroll")                                                             \
      for (int rr = 0; rr < 10; ++rr) {                                             \
        int h = h0 - 1 + rr;                                                        \
        char* dst = &lin[bi][(rr * 58 + 1 + pw) * 64 + sl * 16];                    \
        if (h >= 0 && h < 56) {                                                     \
          const char* src = sIn +                                                   \
              ((size_t)((n * 56 + h) * 56 + pw) * 256 + (icc) * 64 + srcslot * 16); \
          gload_lds16(src, dst);                                                    \
        } else {                                                                    \
          *(i32x4*)dst = (i32x4){0, 0, 0, 0};                                       \
        }                                                                           \
      }                                                                             \
    }                                                                               \
  }

  // weight base: (tap*256 + oc0 + m*16 + cl)*256 + icc*64 + kk*16
  const char* wbase = wSgn + ((size_t)(oc0 + cl) << 8) + kk * 16;
#define WLOAD(dst, tap, icc)                                                        \
  {                                                                                 \
    _Pragma("unroll")                                                               \
    for (int m_ = 0; m_ < 4; ++m_)                                                  \
      dst[m_] = *(const i32x4*)(wbase + (size_t)(tap) * 65536 + m_ * 4096 + (icc) * 64); \
  }

  int r0[7], c0[7];
#pragma unroll
  for (int nf = 0; nf < 7; ++nf) {
    int p = wv * 112 + nf * 16 + cl;
    r0[nf] = p / 56;
    c0[nf] = p % 56;
  }

  i32x4 acc[4][7];
#pragma unroll
  for (int m = 0; m < 4; ++m)
#pragma unroll
    for (int nf = 0; nf < 7; ++nf) acc[m][nf] = (i32x4){0, 0, 0, 0};

  STAGE_3x3(0, 0);
  __syncthreads();  // buf0 ready

  i32x4 wA[4], wB[4];
  for (int icc = 0; icc < 4; ++icc) {
    const int cur = icc & 1;
    WLOAD(wA, 0, icc);            // issued BEFORE staging: no drain on use
    WLOAD(wB, 1, icc);
    if (icc < 3) STAGE_3x3(icc + 1, cur ^ 1);

#pragma unroll
    for (int tap = 0; tap < 9; ++tap) {
      i32x4 w0 = wA[0], w1 = wA[1], w2 = wA[2], w3 = wA[3];
      wA[0] = wB[0]; wA[1] = wB[1]; wA[2] = wB[2]; wA[3] = wB[3];
      if (tap < 7) WLOAD(wB, tap + 2, icc);
      const int kh = tap / 3, kw = tap % 3;
#pragma unroll
      for (int nf = 0; nf < 7; ++nf) {
        int col = c0[nf] + kw;
        int addr = ((r0[nf] + kh) * 58 + col) * 64 + ((kk ^ ((col >> 1) & 3)) << 4);
        i32x4 b = *(const i32x4*)(&lin[cur][addr]);
        acc[0][nf] = MFMAI8(w0, b, acc[0][nf]);
        acc[1][nf] = MFMAI8(w1, b, acc[1][nf]);
        acc[2][nf] = MFMAI8(w2, b, acc[2][nf]);
        acc[3][nf] = MFMAI8(w3, b, acc[3][nf]);
      }
    }
    __syncthreads();  // staging retired long ago; cheap drain
  }

  // ---- epilogue: exact int stats + LDS-transpose + coalesced stores ----
  unsigned short* tb = (unsigned short*)&lin[0][0];  // 16 x 472 u16 = 15104 B
  const size_t ocbase = (size_t)n * 256 + oc0;
#pragma unroll
  for (int m = 0; m < 4; ++m) {
    int sm[4] = {0, 0, 0, 0};
    unsigned sq[4] = {0, 0, 0, 0};
#pragma unroll
    for (int nf = 0; nf < 7; ++nf) {
      i32x4 v = acc[m][nf];
#pragma unroll
      for (int r2 = 0; r2 < 4; ++r2) {
        sm[r2] += v[r2];
        sq[r2] += (unsigned)(v[r2] * v[r2]);
      }
    }
#pragma unroll
    for (int r2 = 0; r2 < 4; ++r2) {
      int aa = sm[r2];
      unsigned qq = sq[r2];
      aa += __shfl_xor(aa, 1); qq += __shfl_xor(qq, 1);
      aa += __shfl_xor(aa, 2); qq += __shfl_xor(qq, 2);
      aa += __shfl_xor(aa, 4); qq += __shfl_xor(qq, 4);
      aa += __shfl_xor(aa, 8); qq += __shfl_xor(qq, 8);
      if (cl == 0) {
        int oc = oc0 + m * 16 + kk * 4 + r2;
        atomicAdd((unsigned long long*)&S[oc], (unsigned long long)(long long)aa);
        atomicAdd((unsigned long long*)&SS[oc], (unsigned long long)qq);
      }
    }
    __syncthreads();  // prev-m tb reads (or final compute) done
#pragma unroll
    for (int nf = 0; nf < 7; ++nf) {
      i32x4 v = acc[m][nf];
      int px = wv * 112 + nf * 16 + cl;
#pragma unroll
      for (int r2 = 0; r2 < 4; ++r2)
        tb[(kk * 4 + r2) * 472 + px] = (unsigned short)(short)v[r2];
    }
    __syncthreads();
    for (int u = t; u < 896; u += 256) {
      int qc = u >> 6, r = u & 63, ocl = r >> 2, c3 = r & 3;
      int c8 = qc * 4 + c3;
      *(i32x4*)(raw + (ocbase + m * 16 + ocl) * 3136 + h0 * 56 + c8 * 8) =
          *(const i32x4*)&tb[ocl * 472 + c8 * 8];
    }
  }
}

// ---------------------------------------------------------------------------
// conv1x1 (i8): stage FULL 112px x 256ic input once (gload_lds, px-keyed XOR),
// ONE staging barrier; weights direct global->VGPR after the drain. Exact int
// stats; LDS-transpose + coalesced stores.
// ---------------------------------------------------------------------------
__global__ __launch_bounds__(256, 2) void conv1x1(const char* __restrict__ sIn,
                                                  const char* __restrict__ wSgn,
                                                  short* __restrict__ raw,
                                                  long long* __restrict__ S,
                                                  long long* __restrict__ SS) {
  __shared__ char lin[112 * 256];  // 28672 B

  const int b = blockIdx.x;            // 896 = 32 n * 28 px-groups
  const int n = b / 28;
  const int hw0 = (b % 28) * 112;
  const size_t px0 = (size_t)n * 3136 + hw0;
  const int t = threadIdx.x, lane = t & 63, wv = t >> 6;
  const int cl = lane & 15, kk = lane >> 4;

#pragma unroll
  for (int i = 0; i < 7; ++i) {
    int u = i * 256 + t;
    int px = u >> 4, s = u & 15;
    const char* src = sIn + (px0 + px) * 256 + ((s ^ (px & 7)) * 16);
    gload_lds16(src, lin + u * 16);
  }

  i32x4 acc[4][7];
#pragma unroll
  for (int m = 0; m < 4; ++m)
#pragma unroll
    for (int nf = 0; nf < 7; ++nf) acc[m][nf] = (i32x4){0, 0, 0, 0};

  __syncthreads();  // staging drained; LDS read-only below

#pragma unroll
  for (int icc = 0; icc < 4; ++icc) {
    i32x4 bfr[7];
#pragma unroll
    for (int nf = 0; nf < 7; ++nf) {
      int px = nf * 16 + cl;
      int srd = (icc * 4 + kk) ^ (px & 7);
      bfr[nf] = *(const i32x4*)(lin + px * 256 + srd * 16);
    }
#pragma unroll
    for (int m = 0; m < 4; ++m) {
      i32x4 a = *(const i32x4*)(wSgn +
          (((size_t)(wv * 64 + m * 16 + cl)) << 8) + icc * 64 + kk * 16);
#pragma unroll
      for (int nf = 0; nf < 7; ++nf) acc[m][nf] = MFMAI8(a, bfr[nf], acc[m][nf]);
    }
  }

  __syncthreads();  // all lin reads done; reuse as transpose buffer
  unsigned short* tb = (unsigned short*)lin;  // 64 rows x 120 u16
#pragma unroll
  for (int m = 0; m < 4; ++m) {
    int sm[4] = {0, 0, 0, 0};
    unsigned sq[4] = {0, 0, 0, 0};
#pragma unroll
    for (int nf = 0; nf < 7; ++nf) {
      i32x4 v = acc[m][nf];
#pragma unroll
      for (int r2 = 0; r2 < 4; ++r2) {
        sm[r2] += v[r2];
        sq[r2] += (unsigned)(v[r2] * v[r2]);
      }
    }
#pragma unroll
    for (int r2 = 0; r2 < 4; ++r2) {
      int aa = sm[r2];
      unsigned qq = sq[r2];
      aa += __shfl_xor(aa, 1); qq += __shfl_xor(qq, 1);
      aa += __shfl_xor(aa, 2); qq += __shfl_xor(qq, 2);
      aa += __shfl_xor(aa, 4); qq += __shfl_xor(qq, 4);
      aa += __shfl_xor(aa, 8); qq += __shfl_xor(qq, 8);
      if (cl == 0) {
        int oc = wv * 64 + m * 16 + kk * 4 + r2;
        atomicAdd((unsigned long long*)&S[oc], (unsigned long long)(long long)aa);
        atomicAdd((unsigned long long*)&SS[oc], (unsigned long long)qq);
      }
    }
    __syncthreads();
#pragma unroll
    for (int nf = 0; nf < 7; ++nf) {
      i32x4 v = acc[m][nf];
      int px = nf * 16 + cl;
#pragma unroll
      for (int r2 = 0; r2 < 4; ++r2)
        tb[(wv * 16 + kk * 4 + r2) * 120 + px] = (unsigned short)(short)v[r2];
    }
    __syncthreads();
#pragma unroll
    for (int i = 0; i < 4; ++i) {
      int u = i * 256 + t;
      int ocg = u >> 4, c8 = u & 15;
      if (c8 < 14) {
        int oc = (ocg >> 4) * 64 + m * 16 + (ocg & 15);
        *(i32x4*)(raw + ((size_t)n * 256 + oc) * 3136 + hw0 + c8 * 8) =
            *(const i32x4*)&tb[ocg * 120 + c8 * 8];
      }
    }
  }
}

// ---------------------------------------------------------------------------
// bn_coef: exact int64 stats -> double -> A*raw + B (fp32 out)
// ---------------------------------------------------------------------------
__global__ void bn_coef(const long long* __restrict__ S, const long long* __restrict__ SS,
                        const float* __restrict__ scale, const float* __restrict__ g,
                        const float* __restrict__ be, const float* __restrict__ bext,
                        float* __restrict__ A, float* __restrict__ B) {
  int o = threadIdx.x;
  const double invN = 1.0 / 100352.0;
  double mu_r  = (double)S[o] * invN;
  double var_r = (double)SS[o] * invN - mu_r * mu_r;
  double sc    = (double)scale[o];
  double rstd  = 1.0 / sqrt(sc * sc * var_r + 1e-5);
  double a     = (double)g[o] * rstd * sc;
  A[o] = (float)a;
  B[o] = (float)((double)be[o] - a * mu_r + (double)bext[o]);
}

// ---------------------------------------------------------------------------
// mid_fuse: u = prelu(x + A1*raw + B1', p1) + b13 -> t1 (d_out, NCHW f32)
//           s2 = i8 sign(u + b21) (NHWC, pair-packed LDS transpose)
// ---------------------------------------------------------------------------
__global__ __launch_bounds__(256) void mid_fuse(const short* __restrict__ raw,
                                                const float* __restrict__ x,
                                                const float* __restrict__ A1,
                                                const float* __restrict__ B1,
                                                const float* __restrict__ p1,
                                                const float* __restrict__ b13,
                                                const float* __restrict__ b21,
                                                float* __restrict__ t1,
                                                char* __restrict__ s2) {
  __shared__ unsigned short l[56 * 128];
  __shared__ float cA[256], cB[256], cP[256], cD[256], cE[256];
  const int h = blockIdx.x, n = blockIdx.y, t = threadIdx.x;
  cA[t] = A1[t]; cB[t] = B1[t]; cP[t] = p1[t]; cD[t] = b13[t]; cE[t] = b21[t];
  __syncthreads();
  const int wv = t & 15, cg = t >> 4;
  if (wv < 14) {
    const int w0 = wv * 4;
    const int swz = (wv & 7) << 3;
#pragma unroll 2
    for (int it = 0; it < 8; ++it) {
      int cp = it * 16 + cg;
      int c0 = cp * 2;
      size_t i0 = (size_t)(n * 256 + c0) * 3136 + h * 56 + w0;
      f32x4 x0 = *(const f32x4*)(x + i0);
      f32x4 x1 = *(const f32x4*)(x + i0 + 3136);
      s16x4 r0 = *(const s16x4*)(raw + i0);
      s16x4 r1 = *(const s16x4*)(raw + i0 + 3136);
      float a0 = cA[c0], b0 = cB[c0], p0 = cP[c0], d0 = cD[c0], e0 = cE[c0];
      float a1 = cA[c0+1], b1 = cB[c0+1], p1v = cP[c0+1], d1 = cD[c0+1], e1 = cE[c0+1];
      f32x4 o0, o1;
      int cs = cp ^ swz;
#pragma unroll
      for (int j = 0; j < 4; ++j) {
        float u0 = x0[j] + a0 * (float)r0[j] + b0;
        u0 = (u0 >= 0.f ? u0 : p0 * u0) + d0;
        o0[j] = u0;
        float u1 = x1[j] + a1 * (float)r1[j] + b1;
        u1 = (u1 >= 0.f ? u1 : p1v * u1) + d1;
        o1[j] = u1;
        unsigned short pk = (unsigned char)sgn8(u0 + e0) |
                            ((unsigned short)(unsigned char)sgn8(u1 + e1) << 8);
        l[(w0 + j) * 128 + cs] = pk;
      }
      *(f32x4*)(t1 + i0) = o0;
      *(f32x4*)(t1 + i0 + 3136) = o1;
    }
  }
  __syncthreads();
  char* op = s2 + ((size_t)(n * 56 + h) * 56) * 256;
  for (int u = t; u < 56 * 16; u += 256) {
    int w2 = u >> 4, cp = u & 15;
    *(i32x4*)(op + w2 * 256 + cp * 16) =
        *(const i32x4*)&l[w2 * 128 + ((cp * 8) ^ (((w2 >> 2) & 7) << 3))];
  }
}

// ---------------------------------------------------------------------------
// final_fuse: out = prelu(A2*raw + B2' + t1, p2) + b23  (block per (n,c) plane)
// ---------------------------------------------------------------------------
__global__ __launch_bounds__(256) void final_fuse(const short* __restrict__ raw,
                                                  const float* __restrict__ A2,
                                                  const float* __restrict__ B2,
                                                  const float* __restrict__ p2,
                                                  const float* __restrict__ b23,
                                                  float* out) {
  const int c = blockIdx.x & 255;
  const size_t base = (size_t)blockIdx.x * 3136;
  const float a = A2[c], b = B2[c], p = p2[c], d = b23[c];
  for (int i = threadIdx.x; i < 784; i += 256) {
    s16x4 r  = *(const s16x4*)(raw + base + (size_t)i * 4);
    f32x4 tt = *(const f32x4*)(out + base + (size_t)i * 4);
    f32x4 o;
#pragma unroll
    for (int j = 0; j < 4; ++j) {
      float v = a * (float)r[j] + b + tt[j];
      o[j] = (v >= 0.f ? v : p * v) + d;
    }
    *(f32x4*)(out + base + (size_t)i * 4) = o;
  }
}

// ---------------------------------------------------------------------------
extern "C" void kernel_launch(void* const* d_in, const int* in_sizes, int n_in,
                              void* d_out, int out_size, void* d_ws, size_t ws_size,
                              hipStream_t stream) {
  const float* x   = (const float*)d_in[0];
  const float* b11 = (const float*)d_in[1];
  const float* b12 = (const float*)d_in[2];
  const float* b13 = (const float*)d_in[3];
  const float* b21 = (const float*)d_in[4];
  const float* b22 = (const float*)d_in[5];
  const float* b23 = (const float*)d_in[6];
  const float* w3  = (const float*)d_in[7];
  const float* wpw = (const float*)d_in[8];
  const float* g1  = (const float*)d_in[9];
  const float* be1 = (const float*)d_in[10];
  const float* g2  = (const float*)d_in[11];
  const float* be2 = (const float*)d_in[12];
  const float* p1  = (const float*)d_in[13];
  const float* p2  = (const float*)d_in[14];

  char* ws = (char*)d_ws;
  short*      raw    = (short*)(ws);                //  51,380,224 B
  char*       sgn    = (char*)(ws + 51380224);      //  25,690,112 B
  char*       w1s    = (char*)(ws + 77070336);      //     589,824 B
  char*       w2s    = (char*)(ws + 77660160);      //      65,536 B
  float*      scale1 = (float*)(ws + 77725696);
  float*      scale2 = (float*)(ws + 77726720);
  long long*  S1     = (long long*)(ws + 77727744); // 2048 B each
  long long*  SS1    = (long long*)(ws + 77729792);
  long long*  S2     = (long long*)(ws + 77731840);
  long long*  SS2    = (long long*)(ws + 77733888);
  float*      A1     = (float*)(ws + 77735936);
  float*      B1     = (float*)(ws + 77736960);
  float*      A2     = (float*)(ws + 77737984);
  float*      B2     = (float*)(ws + 77739008);
  float*      t1     = (float*)d_out;

  hipMemsetAsync(ws + 77727744, 0, 8192, stream);  // zero S1,SS1,S2,SS2

  prep_w<<<dim3(256, 2), 256, 0, stream>>>(w3, wpw, w1s, w2s, scale1, scale2);
  sign_nhwc<<<dim3(56, 32), 256, 0, stream>>>(x, b11, sgn);
  conv3x3<<<dim3(896), 256, 0, stream>>>(sgn, w1s, raw, S1, SS1);
  bn_coef<<<1, 256, 0, stream>>>(S1, SS1, scale1, g1, be1, b12, A1, B1);
  mid_fuse<<<dim3(56, 32), 256, 0, stream>>>(raw, x, A1, B1, p1, b13, b21, t1, sgn);
  conv1x1<<<dim3(896), 256, 0, stream>>>(sgn, w2s, raw, S2, SS2);
  bn_coef<<<1, 256, 0, stream>>>(S2, SS2, scale2, g2, be2, b22, A2, B2);
  final_fuse<<<dim3(8192), 256, 0, stream>>>(raw, A2, B2, p2, b23, (float*)d_out);
}

// Round 10
// 428.351 us; speedup vs baseline: 1.0559x; 1.0160x over previous
//
#include <hip/hip_runtime.h>

typedef __attribute__((ext_vector_type(4))) float  f32x4;
typedef __attribute__((ext_vector_type(4))) short  s16x4;
typedef __attribute__((ext_vector_type(4))) int    i32x4;

#define MFMAI8(a, b, c) __builtin_amdgcn_mfma_i32_16x16x64_i8((a), (b), (c), 0, 0, 0)

__device__ __forceinline__ void gload_lds16(const void* g, void* l) {
  __builtin_amdgcn_global_load_lds((const __attribute__((address_space(1))) void*)g,
                                   (__attribute__((address_space(3))) void*)l, 16, 0, 0);
}

__device__ __forceinline__ char sgn8(float v) {
  return v > 0.f ? (char)1 : (v < 0.f ? (char)-1 : (char)0);
}

// ---------------------------------------------------------------------------
// prep_w: per-oc scale = mean|w|; sign(w) as int8.
// ---------------------------------------------------------------------------
__global__ __launch_bounds__(256) void prep_w(const float* __restrict__ w3,
                                              const float* __restrict__ wpw,
                                              char* __restrict__ w1s,
                                              char* __restrict__ w2s,
                                              float* __restrict__ scale1,
                                              float* __restrict__ scale2) {
  const int o = blockIdx.x;
  const int t = threadIdx.x;
  float s = 0.f;
  if (blockIdx.y == 0) {
    for (int u = t; u < 2304; u += 256) {
      int i = u / 9, tap = u % 9;
      float v = w3[(size_t)(o * 256 + i) * 9 + tap];
      s += fabsf(v);
      w1s[(size_t)(tap * 256 + o) * 256 + i] = sgn8(v);
    }
  } else {
    float v = wpw[o * 256 + t];
    s = fabsf(v);
    w2s[o * 256 + t] = sgn8(v);
  }
  for (int m = 1; m < 64; m <<= 1) s += __shfl_xor(s, m);
  __shared__ float red[4];
  if ((t & 63) == 0) red[t >> 6] = s;
  __syncthreads();
  if (t == 0) {
    float tot = red[0] + red[1] + red[2] + red[3];
    if (blockIdx.y == 0) scale1[o] = tot / 2304.f;
    else                 scale2[o] = tot / 256.f;
  }
}

// ---------------------------------------------------------------------------
// sign_nhwc: s1[n][h][w][c] = i8 sign(x[n][c][h][w] + b11[c])
// ---------------------------------------------------------------------------
__global__ __launch_bounds__(256) void sign_nhwc(const float* __restrict__ x,
                                                 const float* __restrict__ b11,
                                                 char* __restrict__ out) {
  __shared__ unsigned short l[56 * 128];  // [w][cpair]
  __shared__ float cB[256];
  const int h = blockIdx.x, n = blockIdx.y, t = threadIdx.x;
  cB[t] = b11[t];
  __syncthreads();
  const int wv = t & 15, cg = t >> 4;
  if (wv < 14) {
    const int w0 = wv * 4;
    const int swz = (wv & 7) << 3;
#pragma unroll 4
    for (int it = 0; it < 8; ++it) {
      int cp = it * 16 + cg;
      int c0 = cp * 2;
      size_t i0 = (size_t)(n * 256 + c0) * 3136 + h * 56 + w0;
      f32x4 x0 = *(const f32x4*)(x + i0);
      f32x4 x1 = *(const f32x4*)(x + i0 + 3136);
      float bb0 = cB[c0], bb1 = cB[c0 + 1];
      int cs = cp ^ swz;
#pragma unroll
      for (int j = 0; j < 4; ++j) {
        unsigned short pk = (unsigned char)sgn8(x0[j] + bb0) |
                            ((unsigned short)(unsigned char)sgn8(x1[j] + bb1) << 8);
        l[(w0 + j) * 128 + cs] = pk;
      }
    }
  }
  __syncthreads();
  char* op = out + ((size_t)(n * 56 + h) * 56) * 256;
  for (int u = t; u < 56 * 16; u += 256) {
    int w2 = u >> 4, cp = u & 15;
    *(i32x4*)(op + w2 * 256 + cp * 16) =
        *(const i32x4*)&l[w2 * 128 + ((cp * 8) ^ (((w2 >> 2) & 7) << 3))];
  }
}

// ---------------------------------------------------------------------------
// conv3x3 (i8), conv1x1-style single stage. FIX vs R9: stage ALL 3712 chunks
// unconditionally (clamped global source; every lane active so the
// wave-uniform-base + lane*16 LDS contract holds), then zero halo chunks with
// plain ds_write after the drain. Pure compute loop after: 36 K-tiles x 7 nf,
// B from LDS, weights direct global->VGPR ping-pong (only in-loop VMEM).
// LDS 59,392 B -> 2 blocks/CU. Block = 256 oc x 112 px (2 out rows).
// ---------------------------------------------------------------------------
__global__ __launch_bounds__(256, 2) void conv3x3(const char* __restrict__ sIn,
                                                  const char* __restrict__ wSgn,
                                                  short* __restrict__ raw,
                                                  long long* __restrict__ S,
                                                  long long* __restrict__ SS) {
  __shared__ char lin[4 * 58 * 256];  // [row4][col58][256 ic], slot-XOR by (col&7)

  // XCD-chunked bijective swizzle: 896 = 8 * 112
  int g = (blockIdx.x & 7) * 112 + (blockIdx.x >> 3);
  const int ht = g % 28, n = g / 28;
  const int h0 = ht * 2;

  const int t = threadIdx.x;
  const int lane = t & 63, wv = t >> 6;
  const int cl = lane & 15, kk = lane >> 4;

  // ---- stage all 3712 chunks, clamped source (no divergence within waves;
  //      u<3712 cut is at t<128 in i=14: whole-wave granularity) ----
#pragma unroll
  for (int i = 0; i < 15; ++i) {
    int u = i * 256 + t;
    if (u < 3712) {
      int row = u / 928, rem = u % 928;
      int col = rem >> 4, sl = rem & 15;
      int h = h0 - 1 + row;
      int hc = min(max(h, 0), 55);
      int cc = min(max(col, 1), 56);
      const char* src = sIn + ((size_t)((n * 56 + hc) * 56 + (cc - 1)) << 8) +
                        ((sl ^ (col & 7)) << 4);
      gload_lds16(src, lin + u * 16);
    }
  }

  int r0[7], c0[7];
#pragma unroll
  for (int nf = 0; nf < 7; ++nf) {
    int p = nf * 16 + cl;
    r0[nf] = p / 56;
    c0[nf] = p % 56;
  }

  i32x4 acc[4][7];
#pragma unroll
  for (int m = 0; m < 4; ++m)
#pragma unroll
    for (int nf = 0; nf < 7; ++nf) acc[m][nf] = (i32x4){0, 0, 0, 0};

  // weight base for this wave: (tap*256 + wv*64 + m*16 + cl)*256 + icc*64 + kk*16
  const char* wbase = wSgn + (((size_t)(wv * 64 + cl)) << 8) + kk * 16;
#define WL(dst, kt_)                                                             \
  {                                                                              \
    const int icc_ = (kt_) / 9, tap_ = (kt_) % 9;                                \
    _Pragma("unroll")                                                            \
    for (int m_ = 0; m_ < 4; ++m_)                                               \
      dst[m_] = *(const i32x4*)(wbase + tap_ * 65536 + m_ * 4096 + icc_ * 64);   \
  }

  i32x4 wA[4], wB[4];
  WL(wA, 0);        // prefetch kt=0; drained at the barrier below

  __syncthreads();  // staging (and wA) drained

  // ---- zero halo chunks with plain ds_write (per-lane scatter is safe) ----
  // cols 0 and 57, all 4 rows: 128 chunks
  if (t < 128) {
    int row = t >> 5, cs = (t >> 4) & 1, sl = t & 15;
    int col = cs ? 57 : 0;
    *(i32x4*)(lin + (row * 58 + col) * 256 + sl * 16) = (i32x4){0, 0, 0, 0};
  }
  if (h0 == 0) {        // row 0 invalid (h=-1): zero whole row (928 chunks)
    for (int u = t; u < 928; u += 256)
      *(i32x4*)(lin + u * 16) = (i32x4){0, 0, 0, 0};
  }
  if (h0 == 54) {       // row 3 invalid (h=56): zero whole row
    for (int u = t; u < 928; u += 256)
      *(i32x4*)(lin + (3 * 928 + u) * 16) = (i32x4){0, 0, 0, 0};
  }
  __syncthreads();  // halo zeros visible

#pragma unroll
  for (int kt = 0; kt < 36; ++kt) {
    const int icc = kt / 9, tap = kt % 9;
    const int kh = tap / 3, kw = tap % 3;
    if (kt < 35) {
      if (kt & 1) { WL(wA, kt + 1); } else { WL(wB, kt + 1); }
    }
#pragma unroll
    for (int nf = 0; nf < 7; ++nf) {
      int col = c0[nf] + kw;            // 0..57 (halo cols hold zeros)
      int addr = ((r0[nf] + kh) * 58 + col) * 256 +
                 (((icc * 4 + kk) ^ (col & 7)) << 4);
      i32x4 b = *(const i32x4*)(lin + addr);
#pragma unroll
      for (int m = 0; m < 4; ++m) {
        if (kt & 1) acc[m][nf] = MFMAI8(wB[m], b, acc[m][nf]);
        else        acc[m][nf] = MFMAI8(wA[m], b, acc[m][nf]);
      }
    }
  }

  // ---- epilogue: exact int stats + LDS-transpose + coalesced stores ----
  __syncthreads();  // all lin reads done; reuse as transpose buffer
  unsigned short* tb = (unsigned short*)lin;  // 64 rows x 120 u16 per m-round
#pragma unroll
  for (int m = 0; m < 4; ++m) {
    int sm[4] = {0, 0, 0, 0};
    unsigned sq[4] = {0, 0, 0, 0};
#pragma unroll
    for (int nf = 0; nf < 7; ++nf) {
      i32x4 v = acc[m][nf];
#pragma unroll
      for (int r2 = 0; r2 < 4; ++r2) {
        sm[r2] += v[r2];
        sq[r2] += (unsigned)(v[r2] * v[r2]);
      }
    }
#pragma unroll
    for (int r2 = 0; r2 < 4; ++r2) {
      int aa = sm[r2];
      unsigned qq = sq[r2];
      aa += __shfl_xor(aa, 1); qq += __shfl_xor(qq, 1);
      aa += __shfl_xor(aa, 2); qq += __shfl_xor(qq, 2);
      aa += __shfl_xor(aa, 4); qq += __shfl_xor(qq, 4);
      aa += __shfl_xor(aa, 8); qq += __shfl_xor(qq, 8);
      if (cl == 0) {
        int oc = wv * 64 + m * 16 + kk * 4 + r2;
        atomicAdd((unsigned long long*)&S[oc], (unsigned long long)(long long)aa);
        atomicAdd((unsigned long long*)&SS[oc], (unsigned long long)qq);
      }
    }
    __syncthreads();
#pragma unroll
    for (int nf = 0; nf < 7; ++nf) {
      i32x4 v = acc[m][nf];
      int px = nf * 16 + cl;
#pragma unroll
      for (int r2 = 0; r2 < 4; ++r2)
        tb[(wv * 16 + kk * 4 + r2) * 120 + px] = (unsigned short)(short)v[r2];
    }
    __syncthreads();
#pragma unroll
    for (int i = 0; i < 4; ++i) {
      int u = i * 256 + t;
      int ocg = u >> 4, c8 = u & 15;
      if (c8 < 14) {
        int oc = (ocg >> 4) * 64 + m * 16 + (ocg & 15);
        *(i32x4*)(raw + ((size_t)n * 256 + oc) * 3136 + h0 * 56 + c8 * 8) =
            *(const i32x4*)&tb[ocg * 120 + c8 * 8];
      }
    }
  }
}

// ---------------------------------------------------------------------------
// conv1x1 (i8): unchanged (stage once, one barrier, direct weights).
// ---------------------------------------------------------------------------
__global__ __launch_bounds__(256, 2) void conv1x1(const char* __restrict__ sIn,
                                                  const char* __restrict__ wSgn,
                                                  short* __restrict__ raw,
                                                  long long* __restrict__ S,
                                                  long long* __restrict__ SS) {
  __shared__ char lin[112 * 256];  // 28672 B

  const int b = blockIdx.x;            // 896 = 32 n * 28 px-groups
  const int n = b / 28;
  const int hw0 = (b % 28) * 112;
  const size_t px0 = (size_t)n * 3136 + hw0;
  const int t = threadIdx.x, lane = t & 63, wv = t >> 6;
  const int cl = lane & 15, kk = lane >> 4;

#pragma unroll
  for (int i = 0; i < 7; ++i) {
    int u = i * 256 + t;
    int px = u >> 4, s = u & 15;
    const char* src = sIn + (px0 + px) * 256 + ((s ^ (px & 7)) * 16);
    gload_lds16(src, lin + u * 16);
  }

  i32x4 acc[4][7];
#pragma unroll
  for (int m = 0; m < 4; ++m)
#pragma unroll
    for (int nf = 0; nf < 7; ++nf) acc[m][nf] = (i32x4){0, 0, 0, 0};

  __syncthreads();  // staging drained; LDS read-only below

#pragma unroll
  for (int icc = 0; icc < 4; ++icc) {
    i32x4 bfr[7];
#pragma unroll
    for (int nf = 0; nf < 7; ++nf) {
      int px = nf * 16 + cl;
      int srd = (icc * 4 + kk) ^ (px & 7);
      bfr[nf] = *(const i32x4*)(lin + px * 256 + srd * 16);
    }
#pragma unroll
    for (int m = 0; m < 4; ++m) {
      i32x4 a = *(const i32x4*)(wSgn +
          (((size_t)(wv * 64 + m * 16 + cl)) << 8) + icc * 64 + kk * 16);
#pragma unroll
      for (int nf = 0; nf < 7; ++nf) acc[m][nf] = MFMAI8(a, bfr[nf], acc[m][nf]);
    }
  }

  __syncthreads();  // all lin reads done; reuse as transpose buffer
  unsigned short* tb = (unsigned short*)lin;  // 64 rows x 120 u16
#pragma unroll
  for (int m = 0; m < 4; ++m) {
    int sm[4] = {0, 0, 0, 0};
    unsigned sq[4] = {0, 0, 0, 0};
#pragma unroll
    for (int nf = 0; nf < 7; ++nf) {
      i32x4 v = acc[m][nf];
#pragma unroll
      for (int r2 = 0; r2 < 4; ++r2) {
        sm[r2] += v[r2];
        sq[r2] += (unsigned)(v[r2] * v[r2]);
      }
    }
#pragma unroll
    for (int r2 = 0; r2 < 4; ++r2) {
      int aa = sm[r2];
      unsigned qq = sq[r2];
      aa += __shfl_xor(aa, 1); qq += __shfl_xor(qq, 1);
      aa += __shfl_xor(aa, 2); qq += __shfl_xor(qq, 2);
      aa += __shfl_xor(aa, 4); qq += __shfl_xor(qq, 4);
      aa += __shfl_xor(aa, 8); qq += __shfl_xor(qq, 8);
      if (cl == 0) {
        int oc = wv * 64 + m * 16 + kk * 4 + r2;
        atomicAdd((unsigned long long*)&S[oc], (unsigned long long)(long long)aa);
        atomicAdd((unsigned long long*)&SS[oc], (unsigned long long)qq);
      }
    }
    __syncthreads();
#pragma unroll
    for (int nf = 0; nf < 7; ++nf) {
      i32x4 v = acc[m][nf];
      int px = nf * 16 + cl;
#pragma unroll
      for (int r2 = 0; r2 < 4; ++r2)
        tb[(wv * 16 + kk * 4 + r2) * 120 + px] = (unsigned short)(short)v[r2];
    }
    __syncthreads();
#pragma unroll
    for (int i = 0; i < 4; ++i) {
      int u = i * 256 + t;
      int ocg = u >> 4, c8 = u & 15;
      if (c8 < 14) {
        int oc = (ocg >> 4) * 64 + m * 16 + (ocg & 15);
        *(i32x4*)(raw + ((size_t)n * 256 + oc) * 3136 + hw0 + c8 * 8) =
            *(const i32x4*)&tb[ocg * 120 + c8 * 8];
      }
    }
  }
}

// ---------------------------------------------------------------------------
// bn_coef: exact int64 stats -> double -> A*raw + B (fp32 out)
// ---------------------------------------------------------------------------
__global__ void bn_coef(const long long* __restrict__ S, const long long* __restrict__ SS,
                        const float* __restrict__ scale, const float* __restrict__ g,
                        const float* __restrict__ be, const float* __restrict__ bext,
                        float* __restrict__ A, float* __restrict__ B) {
  int o = threadIdx.x;
  const double invN = 1.0 / 100352.0;
  double mu_r  = (double)S[o] * invN;
  double var_r = (double)SS[o] * invN - mu_r * mu_r;
  double sc    = (double)scale[o];
  double rstd  = 1.0 / sqrt(sc * sc * var_r + 1e-5);
  double a     = (double)g[o] * rstd * sc;
  A[o] = (float)a;
  B[o] = (float)((double)be[o] - a * mu_r + (double)bext[o]);
}

// ---------------------------------------------------------------------------
// mid_fuse: u = prelu(x + A1*raw + B1', p1) + b13 -> t1 (d_out, NCHW f32)
//           s2 = i8 sign(u + b21) (NHWC, pair-packed LDS transpose)
// ---------------------------------------------------------------------------
__global__ __launch_bounds__(256) void mid_fuse(const short* __restrict__ raw,
                                                const float* __restrict__ x,
                                                const float* __restrict__ A1,
                                                const float* __restrict__ B1,
                                                const float* __restrict__ p1,
                                                const float* __restrict__ b13,
                                                const float* __restrict__ b21,
                                                float* __restrict__ t1,
                                                char* __restrict__ s2) {
  __shared__ unsigned short l[56 * 128];
  __shared__ float cA[256], cB[256], cP[256], cD[256], cE[256];
  const int h = blockIdx.x, n = blockIdx.y, t = threadIdx.x;
  cA[t] = A1[t]; cB[t] = B1[t]; cP[t] = p1[t]; cD[t] = b13[t]; cE[t] = b21[t];
  __syncthreads();
  const int wv = t & 15, cg = t >> 4;
  if (wv < 14) {
    const int w0 = wv * 4;
    const int swz = (wv & 7) << 3;
#pragma unroll 2
    for (int it = 0; it < 8; ++it) {
      int cp = it * 16 + cg;
      int c0 = cp * 2;
      size_t i0 = (size_t)(n * 256 + c0) * 3136 + h * 56 + w0;
      f32x4 x0 = *(const f32x4*)(x + i0);
      f32x4 x1 = *(const f32x4*)(x + i0 + 3136);
      s16x4 r0 = *(const s16x4*)(raw + i0);
      s16x4 r1 = *(const s16x4*)(raw + i0 + 3136);
      float a0 = cA[c0], b0 = cB[c0], p0 = cP[c0], d0 = cD[c0], e0 = cE[c0];
      float a1 = cA[c0+1], b1 = cB[c0+1], p1v = cP[c0+1], d1 = cD[c0+1], e1 = cE[c0+1];
      f32x4 o0, o1;
      int cs = cp ^ swz;
#pragma unroll
      for (int j = 0; j < 4; ++j) {
        float u0 = x0[j] + a0 * (float)r0[j] + b0;
        u0 = (u0 >= 0.f ? u0 : p0 * u0) + d0;
        o0[j] = u0;
        float u1 = x1[j] + a1 * (float)r1[j] + b1;
        u1 = (u1 >= 0.f ? u1 : p1v * u1) + d1;
        o1[j] = u1;
        unsigned short pk = (unsigned char)sgn8(u0 + e0) |
                            ((unsigned short)(unsigned char)sgn8(u1 + e1) << 8);
        l[(w0 + j) * 128 + cs] = pk;
      }
      *(f32x4*)(t1 + i0) = o0;
      *(f32x4*)(t1 + i0 + 3136) = o1;
    }
  }
  __syncthreads();
  char* op = s2 + ((size_t)(n * 56 + h) * 56) * 256;
  for (int u = t; u < 56 * 16; u += 256) {
    int w2 = u >> 4, cp = u & 15;
    *(i32x4*)(op + w2 * 256 + cp * 16) =
        *(const i32x4*)&l[w2 * 128 + ((cp * 8) ^ (((w2 >> 2) & 7) << 3))];
  }
}

// ---------------------------------------------------------------------------
// final_fuse: out = prelu(A2*raw + B2' + t1, p2) + b23  (block per (n,c) plane)
// ---------------------------------------------------------------------------
__global__ __launch_bounds__(256) void final_fuse(const short* __restrict__ raw,
                                                  const float* __restrict__ A2,
                                                  const float* __restrict__ B2,
                                                  const float* __restrict__ p2,
                                                  const float* __restrict__ b23,
                                                  float* out) {
  const int c = blockIdx.x & 255;
  const size_t base = (size_t)blockIdx.x * 3136;
  const float a = A2[c], b = B2[c], p = p2[c], d = b23[c];
  for (int i = threadIdx.x; i < 784; i += 256) {
    s16x4 r  = *(const s16x4*)(raw + base + (size_t)i * 4);
    f32x4 tt = *(const f32x4*)(out + base + (size_t)i * 4);
    f32x4 o;
#pragma unroll
    for (int j = 0; j < 4; ++j) {
      float v = a * (float)r[j] + b + tt[j];
      o[j] = (v >= 0.f ? v : p * v) + d;
    }
    *(f32x4*)(out + base + (size_t)i * 4) = o;
  }
}

// ---------------------------------------------------------------------------
extern "C" void kernel_launch(void* const* d_in, const int* in_sizes, int n_in,
                              void* d_out, int out_size, void* d_ws, size_t ws_size,
                              hipStream_t stream) {
  const float* x   = (const float*)d_in[0];
  const float* b11 = (const float*)d_in[1];
  const float* b12 = (const float*)d_in[2];
  const float* b13 = (const float*)d_in[3];
  const float* b21 = (const float*)d_in[4];
  const float* b22 = (const float*)d_in[5];
  const float* b23 = (const float*)d_in[6];
  const float* w3  = (const float*)d_in[7];
  const float* wpw = (const float*)d_in[8];
  const float* g1  = (const float*)d_in[9];
  const float* be1 = (const float*)d_in[10];
  const float* g2  = (const float*)d_in[11];
  const float* be2 = (const float*)d_in[12];
  const float* p1  = (const float*)d_in[13];
  const float* p2  = (const float*)d_in[14];

  char* ws = (char*)d_ws;
  short*      raw    = (short*)(ws);                //  51,380,224 B
  char*       sgn    = (char*)(ws + 51380224);      //  25,690,112 B
  char*       w1s    = (char*)(ws + 77070336);      //     589,824 B
  char*       w2s    = (char*)(ws + 77660160);      //      65,536 B
  float*      scale1 = (float*)(ws + 77725696);
  float*      scale2 = (float*)(ws + 77726720);
  long long*  S1     = (long long*)(ws + 77727744); // 2048 B each
  long long*  SS1    = (long long*)(ws + 77729792);
  long long*  S2     = (long long*)(ws + 77731840);
  long long*  SS2    = (long long*)(ws + 77733888);
  float*      A1     = (float*)(ws + 77735936);
  float*      B1     = (float*)(ws + 77736960);
  float*      A2     = (float*)(ws + 77737984);
  float*      B2     = (float*)(ws + 77739008);
  float*      t1     = (float*)d_out;

  hipMemsetAsync(ws + 77727744, 0, 8192, stream);  // zero S1,SS1,S2,SS2

  prep_w<<<dim3(256, 2), 256, 0, stream>>>(w3, wpw, w1s, w2s, scale1, scale2);
  sign_nhwc<<<dim3(56, 32), 256, 0, stream>>>(x, b11, sgn);
  conv3x3<<<dim3(896), 256, 0, stream>>>(sgn, w1s, raw, S1, SS1);
  bn_coef<<<1, 256, 0, stream>>>(S1, SS1, scale1, g1, be1, b12, A1, B1);
  mid_fuse<<<dim3(56, 32), 256, 0, stream>>>(raw, x, A1, B1, p1, b13, b21, t1, sgn);
  conv1x1<<<dim3(896), 256, 0, stream>>>(sgn, w2s, raw, S2, SS2);
  bn_coef<<<1, 256, 0, stream>>>(S2, SS2, scale2, g2, be2, b22, A2, B2);
  final_fuse<<<dim3(8192), 256, 0, stream>>>(raw, A2, B2, p2, b23, (float*)d_out);
}

// Round 11
// 405.435 us; speedup vs baseline: 1.1156x; 1.0565x over previous
//
#include <hip/hip_runtime.h>

typedef __attribute__((ext_vector_type(4))) float  f32x4;
typedef __attribute__((ext_vector_type(4))) short  s16x4;
typedef __attribute__((ext_vector_type(4))) int    i32x4;

#define MFMAI8(a, b, c) __builtin_amdgcn_mfma_i32_16x16x64_i8((a), (b), (c), 0, 0, 0)

__device__ __forceinline__ void gload_lds16(const void* g, void* l) {
  __builtin_amdgcn_global_load_lds((const __attribute__((address_space(1))) void*)g,
                                   (__attribute__((address_space(3))) void*)l, 16, 0, 0);
}

__device__ __forceinline__ char sgn8(float v) {
  return v > 0.f ? (char)1 : (v < 0.f ? (char)-1 : (char)0);
}

// ---------------------------------------------------------------------------
// prep_w: per-oc scale = mean|w|; sign(w) as int8 in WAVE-COALESCED layout:
//  w1p: frag(tap,icc,oct,m) -> 1KB contiguous, byte (kk*16+cl)*16 + b
//       holds w[oc = oct*64+m*16+cl][ic = icc*64+kk*16+b]
//  w2p: frag(icc,oct,m) -> same inner layout.
// ---------------------------------------------------------------------------
__global__ __launch_bounds__(256) void prep_w(const float* __restrict__ w3,
                                              const float* __restrict__ wpw,
                                              char* __restrict__ w1p,
                                              char* __restrict__ w2p,
                                              float* __restrict__ scale1,
                                              float* __restrict__ scale2) {
  const int o = blockIdx.x;
  const int t = threadIdx.x;
  const int oct = o >> 6, mo = (o >> 4) & 3, cl = o & 15;
  float s = 0.f;
  if (blockIdx.y == 0) {
    for (int u = t; u < 2304; u += 256) {
      int i = u / 9, tap = u % 9;
      float v = w3[(size_t)(o * 256 + i) * 9 + tap];
      s += fabsf(v);
      size_t frag = (size_t)(tap * 4 + (i >> 6)) * 16 + oct * 4 + mo;
      w1p[frag * 1024 + ((i >> 4) & 3) * 256 + cl * 16 + (i & 15)] = sgn8(v);
    }
  } else {
    float v = wpw[o * 256 + t];
    s = fabsf(v);
    size_t frag = (size_t)((t >> 6) * 4 + oct) * 4 + mo;
    w2p[frag * 1024 + ((t >> 4) & 3) * 256 + cl * 16 + (t & 15)] = sgn8(v);
  }
  for (int m = 1; m < 64; m <<= 1) s += __shfl_xor(s, m);
  __shared__ float red[4];
  if ((t & 63) == 0) red[t >> 6] = s;
  __syncthreads();
  if (t == 0) {
    float tot = red[0] + red[1] + red[2] + red[3];
    if (blockIdx.y == 0) scale1[o] = tot / 2304.f;
    else                 scale2[o] = tot / 256.f;
  }
}

// ---------------------------------------------------------------------------
// sign_nhwc: s1[n][h][w][c] = i8 sign(x[n][c][h][w] + b11[c])
// ---------------------------------------------------------------------------
__global__ __launch_bounds__(256) void sign_nhwc(const float* __restrict__ x,
                                                 const float* __restrict__ b11,
                                                 char* __restrict__ out) {
  __shared__ unsigned short l[56 * 128];  // [w][cpair]
  __shared__ float cB[256];
  const int h = blockIdx.x, n = blockIdx.y, t = threadIdx.x;
  cB[t] = b11[t];
  __syncthreads();
  const int wv = t & 15, cg = t >> 4;
  if (wv < 14) {
    const int w0 = wv * 4;
    const int swz = (wv & 7) << 3;
#pragma unroll 4
    for (int it = 0; it < 8; ++it) {
      int cp = it * 16 + cg;
      int c0 = cp * 2;
      size_t i0 = (size_t)(n * 256 + c0) * 3136 + h * 56 + w0;
      f32x4 x0 = *(const f32x4*)(x + i0);
      f32x4 x1 = *(const f32x4*)(x + i0 + 3136);
      float bb0 = cB[c0], bb1 = cB[c0 + 1];
      int cs = cp ^ swz;
#pragma unroll
      for (int j = 0; j < 4; ++j) {
        unsigned short pk = (unsigned char)sgn8(x0[j] + bb0) |
                            ((unsigned short)(unsigned char)sgn8(x1[j] + bb1) << 8);
        l[(w0 + j) * 128 + cs] = pk;
      }
    }
  }
  __syncthreads();
  char* op = out + ((size_t)(n * 56 + h) * 56) * 256;
  for (int u = t; u < 56 * 16; u += 256) {
    int w2 = u >> 4, cp = u & 15;
    *(i32x4*)(op + w2 * 256 + cp * 16) =
        *(const i32x4*)&l[w2 * 128 + ((cp * 8) ^ (((w2 >> 2) & 7) << 3))];
  }
}

// ---------------------------------------------------------------------------
// conv3x3 (i8): single-stage full-ic input (59,392 B -> 2 blocks/CU), ONE
// staging drain; weights direct global->VGPR from the COALESCED w1p layout
// (1KB dense per wave-load) with 3-buffer rotation (2-kt prefetch depth).
// Exact int64 BN stats; LDS-transpose + coalesced vec-store epilogue.
// ---------------------------------------------------------------------------
__global__ __launch_bounds__(256, 2) void conv3x3(const char* __restrict__ sIn,
                                                  const char* __restrict__ w1p,
                                                  short* __restrict__ raw,
                                                  long long* __restrict__ S,
                                                  long long* __restrict__ SS) {
  __shared__ char lin[4 * 58 * 256];  // [row4][col58][256 ic], slot-XOR by (col&7)

  // XCD-chunked bijective swizzle: 896 = 8 * 112
  int g = (blockIdx.x & 7) * 112 + (blockIdx.x >> 3);
  const int ht = g % 28, n = g / 28;
  const int h0 = ht * 2;

  const int t = threadIdx.x;
  const int lane = t & 63, wv = t >> 6;
  const int cl = lane & 15, kk = lane >> 4;

  // ---- stage all 3712 chunks, clamped source (wave-uniform exec) ----
#pragma unroll
  for (int i = 0; i < 15; ++i) {
    int u = i * 256 + t;
    if (u < 3712) {
      int row = u / 928, rem = u % 928;
      int col = rem >> 4, sl = rem & 15;
      int h = h0 - 1 + row;
      int hc = min(max(h, 0), 55);
      int cc = min(max(col, 1), 56);
      const char* src = sIn + ((size_t)((n * 56 + hc) * 56 + (cc - 1)) << 8) +
                        ((sl ^ (col & 7)) << 4);
      gload_lds16(src, lin + u * 16);
    }
  }

  int r0[7], c0[7];
#pragma unroll
  for (int nf = 0; nf < 7; ++nf) {
    int p = nf * 16 + cl;
    r0[nf] = p / 56;
    c0[nf] = p % 56;
  }

  i32x4 acc[4][7];
#pragma unroll
  for (int m = 0; m < 4; ++m)
#pragma unroll
    for (int nf = 0; nf < 7; ++nf) acc[m][nf] = (i32x4){0, 0, 0, 0};

  // coalesced weight base for this wave: frag(tap,icc,wv,m) 1KB + lane*16
  const char* wpb = w1p + (size_t)wv * 4 * 1024 + lane * 16;
#define WL(dst, kt_)                                                             \
  {                                                                              \
    const int icc_ = (kt_) / 9, tap_ = (kt_) % 9;                                \
    _Pragma("unroll")                                                            \
    for (int m_ = 0; m_ < 4; ++m_)                                               \
      dst[m_] = *(const i32x4*)(wpb + ((size_t)(tap_ * 4 + icc_) * 16 + m_) * 1024); \
  }

  i32x4 wA[4], wB[4], wC[4];
  WL(wA, 0);
  WL(wB, 1);

  __syncthreads();  // staging (and wA/wB) drained

  // ---- zero halo chunks with plain ds_write ----
  if (t < 128) {
    int row = t >> 5, cs = (t >> 4) & 1, sl = t & 15;
    int col = cs ? 57 : 0;
    *(i32x4*)(lin + (row * 58 + col) * 256 + sl * 16) = (i32x4){0, 0, 0, 0};
  }
  if (h0 == 0) {
    for (int u = t; u < 928; u += 256)
      *(i32x4*)(lin + u * 16) = (i32x4){0, 0, 0, 0};
  }
  if (h0 == 54) {
    for (int u = t; u < 928; u += 256)
      *(i32x4*)(lin + (3 * 928 + u) * 16) = (i32x4){0, 0, 0, 0};
  }
  __syncthreads();  // halo zeros visible

#define CMP(wsel)                                                                \
  {                                                                              \
    _Pragma("unroll")                                                            \
    for (int nf = 0; nf < 7; ++nf) {                                             \
      int col = c0[nf] + kw;                                                     \
      int addr = ((r0[nf] + kh) * 58 + col) * 256 +                              \
                 (((icc * 4 + kk) ^ (col & 7)) << 4);                            \
      i32x4 b = *(const i32x4*)(lin + addr);                                     \
      _Pragma("unroll")                                                          \
      for (int m = 0; m < 4; ++m) acc[m][nf] = MFMAI8(wsel[m], b, acc[m][nf]);   \
    }                                                                            \
  }

#pragma unroll
  for (int kt = 0; kt < 36; ++kt) {
    const int icc = kt / 9, tap = kt % 9;
    const int kh = tap / 3, kw = tap % 3;
    if (kt < 34) {                       // prefetch kt+2 into buffer (kt+2)%3
      if (kt % 3 == 0)      { WL(wC, kt + 2); }
      else if (kt % 3 == 1) { WL(wA, kt + 2); }
      else                  { WL(wB, kt + 2); }
    }
    if (kt % 3 == 0)      { CMP(wA) }
    else if (kt % 3 == 1) { CMP(wB) }
    else                  { CMP(wC) }
  }

  // ---- epilogue: exact int stats + LDS-transpose + coalesced stores ----
  __syncthreads();  // all lin reads done; reuse as transpose buffer
  unsigned short* tb = (unsigned short*)lin;  // 64 rows x 120 u16 per m-round
#pragma unroll
  for (int m = 0; m < 4; ++m) {
    int sm[4] = {0, 0, 0, 0};
    unsigned sq[4] = {0, 0, 0, 0};
#pragma unroll
    for (int nf = 0; nf < 7; ++nf) {
      i32x4 v = acc[m][nf];
#pragma unroll
      for (int r2 = 0; r2 < 4; ++r2) {
        sm[r2] += v[r2];
        sq[r2] += (unsigned)(v[r2] * v[r2]);
      }
    }
#pragma unroll
    for (int r2 = 0; r2 < 4; ++r2) {
      int aa = sm[r2];
      unsigned qq = sq[r2];
      aa += __shfl_xor(aa, 1); qq += __shfl_xor(qq, 1);
      aa += __shfl_xor(aa, 2); qq += __shfl_xor(qq, 2);
      aa += __shfl_xor(aa, 4); qq += __shfl_xor(qq, 4);
      aa += __shfl_xor(aa, 8); qq += __shfl_xor(qq, 8);
      if (cl == 0) {
        int oc = wv * 64 + m * 16 + kk * 4 + r2;
        atomicAdd((unsigned long long*)&S[oc], (unsigned long long)(long long)aa);
        atomicAdd((unsigned long long*)&SS[oc], (unsigned long long)qq);
      }
    }
    __syncthreads();
#pragma unroll
    for (int nf = 0; nf < 7; ++nf) {
      i32x4 v = acc[m][nf];
      int px = nf * 16 + cl;
#pragma unroll
      for (int r2 = 0; r2 < 4; ++r2)
        tb[(wv * 16 + kk * 4 + r2) * 120 + px] = (unsigned short)(short)v[r2];
    }
    __syncthreads();
#pragma unroll
    for (int i = 0; i < 4; ++i) {
      int u = i * 256 + t;
      int ocg = u >> 4, c8 = u & 15;
      if (c8 < 14) {
        int oc = (ocg >> 4) * 64 + m * 16 + (ocg & 15);
        *(i32x4*)(raw + ((size_t)n * 256 + oc) * 3136 + h0 * 56 + c8 * 8) =
            *(const i32x4*)&tb[ocg * 120 + c8 * 8];
      }
    }
  }
}

// ---------------------------------------------------------------------------
// conv1x1 (i8): stage input once; ALL weights -> registers upfront (16 KB per
// wave = 64 VGPR via coalesced w2p); ZERO in-loop VMEM.
// ---------------------------------------------------------------------------
__global__ __launch_bounds__(256, 2) void conv1x1(const char* __restrict__ sIn,
                                                  const char* __restrict__ w2p,
                                                  short* __restrict__ raw,
                                                  long long* __restrict__ S,
                                                  long long* __restrict__ SS) {
  __shared__ char lin[112 * 256];  // 28672 B

  const int b = blockIdx.x;            // 896 = 32 n * 28 px-groups
  const int n = b / 28;
  const int hw0 = (b % 28) * 112;
  const size_t px0 = (size_t)n * 3136 + hw0;
  const int t = threadIdx.x, lane = t & 63, wv = t >> 6;
  const int cl = lane & 15, kk = lane >> 4;

#pragma unroll
  for (int i = 0; i < 7; ++i) {
    int u = i * 256 + t;
    int px = u >> 4, s = u & 15;
    const char* src = sIn + (px0 + px) * 256 + ((s ^ (px & 7)) * 16);
    gload_lds16(src, lin + u * 16);
  }

  // all weights for this wave: frag(icc,wv,m) -> 1KB dense
  i32x4 wreg[4][4];
#pragma unroll
  for (int icc = 0; icc < 4; ++icc)
#pragma unroll
    for (int m = 0; m < 4; ++m)
      wreg[icc][m] = *(const i32x4*)(w2p +
          ((size_t)((icc * 4 + wv) * 4 + m)) * 1024 + lane * 16);

  i32x4 acc[4][7];
#pragma unroll
  for (int m = 0; m < 4; ++m)
#pragma unroll
    for (int nf = 0; nf < 7; ++nf) acc[m][nf] = (i32x4){0, 0, 0, 0};

  __syncthreads();  // staging + weights drained; no VMEM below until epilogue

#pragma unroll
  for (int icc = 0; icc < 4; ++icc) {
    i32x4 bfr[7];
#pragma unroll
    for (int nf = 0; nf < 7; ++nf) {
      int px = nf * 16 + cl;
      int srd = (icc * 4 + kk) ^ (px & 7);
      bfr[nf] = *(const i32x4*)(lin + px * 256 + srd * 16);
    }
#pragma unroll
    for (int m = 0; m < 4; ++m)
#pragma unroll
      for (int nf = 0; nf < 7; ++nf)
        acc[m][nf] = MFMAI8(wreg[icc][m], bfr[nf], acc[m][nf]);
  }

  __syncthreads();  // all lin reads done; reuse as transpose buffer
  unsigned short* tb = (unsigned short*)lin;  // 64 rows x 120 u16
#pragma unroll
  for (int m = 0; m < 4; ++m) {
    int sm[4] = {0, 0, 0, 0};
    unsigned sq[4] = {0, 0, 0, 0};
#pragma unroll
    for (int nf = 0; nf < 7; ++nf) {
      i32x4 v = acc[m][nf];
#pragma unroll
      for (int r2 = 0; r2 < 4; ++r2) {
        sm[r2] += v[r2];
        sq[r2] += (unsigned)(v[r2] * v[r2]);
      }
    }
#pragma unroll
    for (int r2 = 0; r2 < 4; ++r2) {
      int aa = sm[r2];
      unsigned qq = sq[r2];
      aa += __shfl_xor(aa, 1); qq += __shfl_xor(qq, 1);
      aa += __shfl_xor(aa, 2); qq += __shfl_xor(qq, 2);
      aa += __shfl_xor(aa, 4); qq += __shfl_xor(qq, 4);
      aa += __shfl_xor(aa, 8); qq += __shfl_xor(qq, 8);
      if (cl == 0) {
        int oc = wv * 64 + m * 16 + kk * 4 + r2;
        atomicAdd((unsigned long long*)&S[oc], (unsigned long long)(long long)aa);
        atomicAdd((unsigned long long*)&SS[oc], (unsigned long long)qq);
      }
    }
    __syncthreads();
#pragma unroll
    for (int nf = 0; nf < 7; ++nf) {
      i32x4 v = acc[m][nf];
      int px = nf * 16 + cl;
#pragma unroll
      for (int r2 = 0; r2 < 4; ++r2)
        tb[(wv * 16 + kk * 4 + r2) * 120 + px] = (unsigned short)(short)v[r2];
    }
    __syncthreads();
#pragma unroll
    for (int i = 0; i < 4; ++i) {
      int u = i * 256 + t;
      int ocg = u >> 4, c8 = u & 15;
      if (c8 < 14) {
        int oc = (ocg >> 4) * 64 + m * 16 + (ocg & 15);
        *(i32x4*)(raw + ((size_t)n * 256 + oc) * 3136 + hw0 + c8 * 8) =
            *(const i32x4*)&tb[ocg * 120 + c8 * 8];
      }
    }
  }
}

// ---------------------------------------------------------------------------
// bn_coef: exact int64 stats -> double -> A*raw + B (fp32 out)
// ---------------------------------------------------------------------------
__global__ void bn_coef(const long long* __restrict__ S, const long long* __restrict__ SS,
                        const float* __restrict__ scale, const float* __restrict__ g,
                        const float* __restrict__ be, const float* __restrict__ bext,
                        float* __restrict__ A, float* __restrict__ B) {
  int o = threadIdx.x;
  const double invN = 1.0 / 100352.0;
  double mu_r  = (double)S[o] * invN;
  double var_r = (double)SS[o] * invN - mu_r * mu_r;
  double sc    = (double)scale[o];
  double rstd  = 1.0 / sqrt(sc * sc * var_r + 1e-5);
  double a     = (double)g[o] * rstd * sc;
  A[o] = (float)a;
  B[o] = (float)((double)be[o] - a * mu_r + (double)bext[o]);
}

// ---------------------------------------------------------------------------
// mid_fuse: u = prelu(x + A1*raw + B1', p1) + b13 -> t1 (d_out, NCHW f32)
//           s2 = i8 sign(u + b21) (NHWC, pair-packed LDS transpose)
// ---------------------------------------------------------------------------
__global__ __launch_bounds__(256) void mid_fuse(const short* __restrict__ raw,
                                                const float* __restrict__ x,
                                                const float* __restrict__ A1,
                                                const float* __restrict__ B1,
                                                const float* __restrict__ p1,
                                                const float* __restrict__ b13,
                                                const float* __restrict__ b21,
                                                float* __restrict__ t1,
                                                char* __restrict__ s2) {
  __shared__ unsigned short l[56 * 128];
  __shared__ float cA[256], cB[256], cP[256], cD[256], cE[256];
  const int h = blockIdx.x, n = blockIdx.y, t = threadIdx.x;
  cA[t] = A1[t]; cB[t] = B1[t]; cP[t] = p1[t]; cD[t] = b13[t]; cE[t] = b21[t];
  __syncthreads();
  const int wv = t & 15, cg = t >> 4;
  if (wv < 14) {
    const int w0 = wv * 4;
    const int swz = (wv & 7) << 3;
#pragma unroll 2
    for (int it = 0; it < 8; ++it) {
      int cp = it * 16 + cg;
      int c0 = cp * 2;
      size_t i0 = (size_t)(n * 256 + c0) * 3136 + h * 56 + w0;
      f32x4 x0 = *(const f32x4*)(x + i0);
      f32x4 x1 = *(const f32x4*)(x + i0 + 3136);
      s16x4 r0 = *(const s16x4*)(raw + i0);
      s16x4 r1 = *(const s16x4*)(raw + i0 + 3136);
      float a0 = cA[c0], b0 = cB[c0], p0 = cP[c0], d0 = cD[c0], e0 = cE[c0];
      float a1 = cA[c0+1], b1 = cB[c0+1], p1v = cP[c0+1], d1 = cD[c0+1], e1 = cE[c0+1];
      f32x4 o0, o1;
      int cs = cp ^ swz;
#pragma unroll
      for (int j = 0; j < 4; ++j) {
        float u0 = x0[j] + a0 * (float)r0[j] + b0;
        u0 = (u0 >= 0.f ? u0 : p0 * u0) + d0;
        o0[j] = u0;
        float u1 = x1[j] + a1 * (float)r1[j] + b1;
        u1 = (u1 >= 0.f ? u1 : p1v * u1) + d1;
        o1[j] = u1;
        unsigned short pk = (unsigned char)sgn8(u0 + e0) |
                            ((unsigned short)(unsigned char)sgn8(u1 + e1) << 8);
        l[(w0 + j) * 128 + cs] = pk;
      }
      *(f32x4*)(t1 + i0) = o0;
      *(f32x4*)(t1 + i0 + 3136) = o1;
    }
  }
  __syncthreads();
  char* op = s2 + ((size_t)(n * 56 + h) * 56) * 256;
  for (int u = t; u < 56 * 16; u += 256) {
    int w2 = u >> 4, cp = u & 15;
    *(i32x4*)(op + w2 * 256 + cp * 16) =
        *(const i32x4*)&l[w2 * 128 + ((cp * 8) ^ (((w2 >> 2) & 7) << 3))];
  }
}

// ---------------------------------------------------------------------------
// final_fuse: out = prelu(A2*raw + B2' + t1, p2) + b23  (block per (n,c) plane)
// ---------------------------------------------------------------------------
__global__ __launch_bounds__(256) void final_fuse(const short* __restrict__ raw,
                                                  const float* __restrict__ A2,
                                                  const float* __restrict__ B2,
                                                  const float* __restrict__ p2,
                                                  const float* __restrict__ b23,
                                                  float* out) {
  const int c = blockIdx.x & 255;
  const size_t base = (size_t)blockIdx.x * 3136;
  const float a = A2[c], b = B2[c], p = p2[c], d = b23[c];
  for (int i = threadIdx.x; i < 784; i += 256) {
    s16x4 r  = *(const s16x4*)(raw + base + (size_t)i * 4);
    f32x4 tt = *(const f32x4*)(out + base + (size_t)i * 4);
    f32x4 o;
#pragma unroll
    for (int j = 0; j < 4; ++j) {
      float v = a * (float)r[j] + b + tt[j];
      o[j] = (v >= 0.f ? v : p * v) + d;
    }
    *(f32x4*)(out + base + (size_t)i * 4) = o;
  }
}

// ---------------------------------------------------------------------------
extern "C" void kernel_launch(void* const* d_in, const int* in_sizes, int n_in,
                              void* d_out, int out_size, void* d_ws, size_t ws_size,
                              hipStream_t stream) {
  const float* x   = (const float*)d_in[0];
  const float* b11 = (const float*)d_in[1];
  const float* b12 = (const float*)d_in[2];
  const float* b13 = (const float*)d_in[3];
  const float* b21 = (const float*)d_in[4];
  const float* b22 = (const float*)d_in[5];
  const float* b23 = (const float*)d_in[6];
  const float* w3  = (const float*)d_in[7];
  const float* wpw = (const float*)d_in[8];
  const float* g1  = (const float*)d_in[9];
  const float* be1 = (const float*)d_in[10];
  const float* g2  = (const float*)d_in[11];
  const float* be2 = (const float*)d_in[12];
  const float* p1  = (const float*)d_in[13];
  const float* p2  = (const float*)d_in[14];

  char* ws = (char*)d_ws;
  short*      raw    = (short*)(ws);                //  51,380,224 B
  char*       sgn    = (char*)(ws + 51380224);      //  25,690,112 B
  char*       w1p    = (char*)(ws + 77070336);      //     589,824 B
  char*       w2p    = (char*)(ws + 77660160);      //      65,536 B
  float*      scale1 = (float*)(ws + 77725696);
  float*      scale2 = (float*)(ws + 77726720);
  long long*  S1     = (long long*)(ws + 77727744); // 2048 B each
  long long*  SS1    = (long long*)(ws + 77729792);
  long long*  S2     = (long long*)(ws + 77731840);
  long long*  SS2    = (long long*)(ws + 77733888);
  float*      A1     = (float*)(ws + 77735936);
  float*      B1     = (float*)(ws + 77736960);
  float*      A2     = (float*)(ws + 77737984);
  float*      B2     = (float*)(ws + 77739008);
  float*      t1     = (float*)d_out;

  hipMemsetAsync(ws + 77727744, 0, 8192, stream);  // zero S1,SS1,S2,SS2

  prep_w<<<dim3(256, 2), 256, 0, stream>>>(w3, wpw, w1p, w2p, scale1, scale2);
  sign_nhwc<<<dim3(56, 32), 256, 0, stream>>>(x, b11, sgn);
  conv3x3<<<dim3(896), 256, 0, stream>>>(sgn, w1p, raw, S1, SS1);
  bn_coef<<<1, 256, 0, stream>>>(S1, SS1, scale1, g1, be1, b12, A1, B1);
  mid_fuse<<<dim3(56, 32), 256, 0, stream>>>(raw, x, A1, B1, p1, b13, b21, t1, sgn);
  conv1x1<<<dim3(896), 256, 0, stream>>>(sgn, w2p, raw, S2, SS2);
  bn_coef<<<1, 256, 0, stream>>>(S2, SS2, scale2, g2, be2, b22, A2, B2);
  final_fuse<<<dim3(8192), 256, 0, stream>>>(raw, A2, B2, p2, b23, (float*)d_out);
}